// Round 4
// baseline (370.401 us; speedup 1.0000x reference)
//
#include <hip/hip_runtime.h>

typedef float f32x4 __attribute__((ext_vector_type(4)));
typedef short s16x8 __attribute__((ext_vector_type(8)));
typedef unsigned short u16;

#define NB 8
#define NC 64
#define NN 4096
#define NK 8

__device__ __forceinline__ u16 f2bf_rne(float f) {
    unsigned u = __float_as_uint(f);
    u += 0x7FFFu + ((u >> 16) & 1u);
    return (u16)(u >> 16);
}
__device__ __forceinline__ u16 f2bf_trunc(float f) {
    return (u16)(__float_as_uint(f) >> 16);
}
__device__ __forceinline__ float bf2f(u16 v) {
    return __uint_as_float(((unsigned)v) << 16);
}

// ---------------------------------------------------------------------------
// Kernel 1: W' = [Wh(64); Wf(8); Wg(8)] (80x64) @ x[b] via MFMA (unchanged).
// ---------------------------------------------------------------------------
__global__ __launch_bounds__(256, 4)
void precompute_qgh(const float* __restrict__ x,
                    const float* __restrict__ Wf,
                    const float* __restrict__ Wg,
                    const float* __restrict__ Wh,
                    u16* __restrict__ Qw, u16* __restrict__ Gw,
                    u16* __restrict__ Hw)
{
    const int b  = blockIdx.y;
    const int n0 = blockIdx.x * 64;
    const int t  = threadIdx.x;
    const int wave = t >> 6, lane = t & 63, col = lane & 15, quad = lane >> 4;
    const int n = n0 + wave * 16 + col;
    const float* xb = x + (size_t)b * NC * NN;

    __shared__ u16 Wl[80][72];

    float xv[16];
    #pragma unroll
    for (int s = 0; s < 2; s++)
        #pragma unroll
        for (int kk = 0; kk < 8; kk++)
            xv[s * 8 + kk] = xb[(size_t)(s * 32 + quad * 8 + kk) * NN + n];

    #pragma unroll
    for (int u = 0; u < 20; u++) {
        int v = t + u * 256, row = v >> 6, c = v & 63;
        float w = (row < 64) ? Wh[row * 64 + c]
                : (row < 72) ? Wf[(row - 64) * 64 + c]
                             : Wg[(row - 72) * 64 + c];
        Wl[row][c] = f2bf_rne(w);
    }
    __syncthreads();

    s16x8 bfrag[2];
    #pragma unroll
    for (int s = 0; s < 2; s++)
        #pragma unroll
        for (int kk = 0; kk < 8; kk++)
            ((u16*)&bfrag[s])[kk] = f2bf_rne(xv[s * 8 + kk]);

    f32x4 d[5];
    #pragma unroll
    for (int mt = 0; mt < 5; mt++) d[mt] = (f32x4){0.f, 0.f, 0.f, 0.f};
    #pragma unroll
    for (int s = 0; s < 2; s++) {
        #pragma unroll
        for (int mt = 0; mt < 5; mt++) {
            int row = (mt < 4) ? mt * 16 + col : 64 + col;
            s16x8 af = *(const s16x8*)(&Wl[row][s * 32 + quad * 8]);
            d[mt] = __builtin_amdgcn_mfma_f32_16x16x32_bf16(af, bfrag[s], d[mt], 0, 0, 0);
        }
    }

    u16* Hb = Hw + (size_t)b * NC * NN;
    #pragma unroll
    for (int mt = 0; mt < 4; mt++)
        #pragma unroll
        for (int r = 0; r < 4; r++)
            Hb[(size_t)(mt * 16 + quad * 4 + r) * NN + n] = f2bf_rne(d[mt][r]);
    #pragma unroll
    for (int r = 0; r < 4; r++) {
        int m = quad * 4 + r;
        u16 v = f2bf_rne(d[4][r]);
        if (m < 8) Qw[((size_t)b * NN + n) * NK + m]       = v;
        else       Gw[((size_t)b * NN + n) * NK + (m - 8)] = v;
    }
}

// ---------------------------------------------------------------------------
// Kernel 2: flash attention + fused last-arrival reduction.
// v4: frag-major LDS (conflict-free b128 frag reads: lane l reads base+16*l,
// +1 unit pad per 64-lane frag), 16.6 KB LDS, launch_bounds(256,8) -> target
// 32 waves/CU. No register prefetch arrays (VGPR<=64). 2 barriers/chunk.
//   V frag f=csub*2+ks at unit f*65; P frag per wave w at unit (w*2+ks)*65
//   (units of 16B, after V's 8*65 units).
// ---------------------------------------------------------------------------
#define V_UNITS (8 * 65)
#define P_UNITS (8 * 65)

__global__ __launch_bounds__(256, 8)
void attention_fa(const u16* __restrict__ Qw, const u16* __restrict__ Gw,
                  const u16* __restrict__ Hw,
                  u16* __restrict__ Opart, float* __restrict__ Lpart,
                  const float* __restrict__ x, const float* __restrict__ gamma,
                  float* __restrict__ out,
                  int* __restrict__ cnt, int jspan, int parts)
{
    const int b    = blockIdx.y;
    const int ib   = blockIdx.x;          // i-tile index
    const int i0   = ib * 64;
    const int part = blockIdx.z;
    const int t    = threadIdx.x;
    const int wave = t >> 6, lane = t & 63, col = lane & 15, quad = lane >> 4;

    __shared__ u16 lds[(V_UNITS + P_UNITS) * 8];   // 16640 B
    __shared__ float linv[64];
    __shared__ int flagS;

    const u16* Qb = Qw + (size_t)b * NN * NK;
    const u16* Gb = Gw + (size_t)b * NN * NK;
    const u16* Hb = Hw + (size_t)b * NC * NN;

    s16x8 qfrag = *(const s16x8*)(Qb + (size_t)(i0 + wave * 16 + col) * NK);
    if (quad != 0) {
        #pragma unroll
        for (int i = 0; i < 8; i++) ((u16*)&qfrag)[i] = 0;
    }
    s16x8 ones;
    #pragma unroll
    for (int i = 0; i < 8; i++) ((u16*)&ones)[i] = 0x3F80;

    f32x4 oacc[4];
    #pragma unroll
    for (int ct = 0; ct < 4; ct++) oacc[ct] = (f32x4){0.f, 0.f, 0.f, 0.f};
    f32x4 lacc = (f32x4){0.f, 0.f, 0.f, 0.f};

    const int jbase  = part * jspan;
    const int chunks = jspan / 64;

    // staging coords: slot s in {t, t+256}: c = s>>3, jseg = s&7
    const int sc0 = t >> 3, sseg = t & 7;
    const int sks = sseg >> 2, squad = sseg & 3;
    // LDS u16 offsets for the two staged slots
    const int vw0 = (((sc0 >> 4) * 2 + sks) * 65 + squad * 16 + (sc0 & 15)) * 8;
    const int sc1 = (t + 256) >> 3;
    const int vw1 = (((sc1 >> 4) * 2 + sks) * 65 + squad * 16 + (sc1 & 15)) * 8;

    const int pbase = V_UNITS * 8 + (wave * 2) * 8 * 65;   // wave's P region (ks=0)

    for (int cc = 0; cc < chunks; cc++) {
        const int j0 = jbase + cc * 64;

        __syncthreads();   // previous PV reads done -> safe to overwrite V & P

        // ---- stage V chunk (frag-major) ----
        *(s16x8*)(&lds[vw0]) = *(const s16x8*)(Hb + (size_t)sc0 * NN + j0 + sseg * 8);
        *(s16x8*)(&lds[vw1]) = *(const s16x8*)(Hb + (size_t)sc1 * NN + j0 + sseg * 8);

        // ---- S = QK^T -> exp -> P (frag-major, per-wave region) ----
        #pragma unroll
        for (int jt = 0; jt < 4; jt++) {
            s16x8 gf = *(const s16x8*)(Gb + (size_t)(j0 + jt * 16 + col) * NK);
            f32x4 s = __builtin_amdgcn_mfma_f32_16x16x32_bf16(
                qfrag, gf, (f32x4){0.f, 0.f, 0.f, 0.f}, 0, 0, 0);
            const int lidx = ((jt & 1) * 2 + (col >> 3)) * 16;   // frag-lane base
            const int base = pbase + (jt >> 1) * 8 * 65 + (lidx + quad * 4) * 8 + (col & 7);
            #pragma unroll
            for (int r = 0; r < 4; r++)
                lds[base + r * 8] = f2bf_trunc(__expf(s[r]));
        }

        __syncthreads();   // V + P visible

        // ---- PV + row-sum MFMAs (all frag reads contiguous, conflict-free) ----
        #pragma unroll
        for (int s2 = 0; s2 < 2; s2++) {
            s16x8 af = *(const s16x8*)(&lds[pbase + s2 * 8 * 65 + lane * 8]);
            lacc = __builtin_amdgcn_mfma_f32_16x16x32_bf16(af, ones, lacc, 0, 0, 0);
            #pragma unroll
            for (int ct = 0; ct < 4; ct++) {
                s16x8 bf = *(const s16x8*)(&lds[((ct * 2 + s2) * 65 + lane) * 8]);
                oacc[ct] = __builtin_amdgcn_mfma_f32_16x16x32_bf16(af, bf, oacc[ct], 0, 0, 0);
            }
        }
    }

    // ---- write partial l ----
    float* Lb = Lpart + ((size_t)part * NB + b) * NN + i0;
    if (col == 0) {
        #pragma unroll
        for (int r = 0; r < 4; r++) Lb[wave * 16 + quad * 4 + r] = lacc[r];
    }

    // ---- transpose O to [c][i] via LDS (alias frag buffer), store partial O ----
    __syncthreads();
    u16 (*OT)[72] = (u16(*)[72])lds;       // 64*72 = 4608 u16 <= 8320
    #pragma unroll
    for (int ct = 0; ct < 4; ct++)
        #pragma unroll
        for (int r = 0; r < 4; r++)
            OT[ct * 16 + col][wave * 16 + quad * 4 + r] = f2bf_rne(oacc[ct][r]);
    __syncthreads();

    u16* Ob = Opart + ((size_t)part * NB + b) * NC * NN;
    {
        const int vc = t >> 3, vseg = t & 7;
        #pragma unroll
        for (int u = 0; u < 2; u++) {
            int c = u * 32 + vc;
            *(s16x8*)(Ob + (size_t)c * NN + i0 + vseg * 8) = *(const s16x8*)(&OT[c][vseg * 8]);
        }
    }

    // ---- last-arrival fused reduction for this (b, i-tile) slice ----
    __threadfence();
    __syncthreads();
    if (t == 0) {
        int old = __hip_atomic_fetch_add(&cnt[b * (NN / 64) + ib], 1,
                                         __ATOMIC_ACQ_REL, __HIP_MEMORY_SCOPE_AGENT);
        flagS = (old == parts - 1) ? 1 : 0;
    }
    __syncthreads();
    if (!flagS) return;

    // 1/l for the 64 rows of this tile
    if (t < 64) {
        float ls = 0.f;
        for (int p = 0; p < parts; p++)
            ls += Lpart[((size_t)p * NB + b) * NN + i0 + t];
        linv[t] = 1.0f / ls;
    }
    __syncthreads();

    const float g = gamma[0];
    const float* xb = x + (size_t)b * NC * NN;
    float* ob = out + (size_t)b * NC * NN;
    const int rc = t >> 2;                 // channel 0..63
    const int iv = (t & 3) * 16;           // i offset within tile

    float acc[16];
    #pragma unroll
    for (int e = 0; e < 16; e++) acc[e] = 0.f;
    for (int p = 0; p < parts; p++) {
        const u16* Os = Opart + (((size_t)p * NB + b) * NC + rc) * NN + i0 + iv;
        s16x8 o0 = *(const s16x8*)(Os);
        s16x8 o1 = *(const s16x8*)(Os + 8);
        #pragma unroll
        for (int e = 0; e < 8; e++) {
            acc[e]     += bf2f((u16)o0[e]);
            acc[e + 8] += bf2f((u16)o1[e]);
        }
    }
    const size_t obase = (size_t)rc * NN + i0 + iv;
    #pragma unroll
    for (int v4i = 0; v4i < 4; v4i++) {
        f32x4 xv = *(const f32x4*)(xb + obase + v4i * 4);
        f32x4 o;
        #pragma unroll
        for (int e = 0; e < 4; e++)
            o[e] = g * (acc[v4i * 4 + e] * linv[iv + v4i * 4 + e]) + xv[e];
        *(f32x4*)(ob + obase + v4i * 4) = o;
    }
}

extern "C" void kernel_launch(void* const* d_in, const int* in_sizes, int n_in,
                              void* d_out, int out_size, void* d_ws, size_t ws_size,
                              hipStream_t stream) {
    const float* x     = (const float*)d_in[0];
    const float* Wf    = (const float*)d_in[1];
    const float* Wg    = (const float*)d_in[2];
    const float* Wh    = (const float*)d_in[3];
    const float* gamma = (const float*)d_in[4];
    float* out = (float*)d_out;

    u16* Qw = (u16*)d_ws;                       // [B][N][8]
    u16* Gw = Qw + (size_t)NB * NN * NK;        // [B][N][8]
    u16* Hw = Gw + (size_t)NB * NN * NK;        // [B][C][N]
    u16* Opart = Hw + (size_t)NB * NC * NN;     // [parts][B][C][N] bf16

    const size_t fixed = (size_t)(2 * NB * NN * NK + NB * NC * NN) * 2;
    int parts = 4;
    while (parts > 1) {
        size_t need = fixed + (size_t)parts * NB * NC * NN * 2
                            + (size_t)parts * NB * NN * 4
                            + NB * (NN / 64) * 4 + 8192;
        if (need <= ws_size) break;
        parts >>= 1;
    }
    float* Lpart = (float*)(Opart + (size_t)parts * NB * NC * NN);
    int* cnt = (int*)(Lpart + (size_t)parts * NB * NN);
    const int jspan = NN / parts;

    hipMemsetAsync(cnt, 0, NB * (NN / 64) * sizeof(int), stream);
    precompute_qgh<<<dim3(64, NB), 256, 0, stream>>>(x, Wf, Wg, Wh, Qw, Gw, Hw);
    attention_fa<<<dim3(NN / 64, NB, parts), 256, 0, stream>>>(
        Qw, Gw, Hw, Opart, Lpart, x, gamma, out, cnt, jspan, parts);
}

// Round 5
// 146.677 us; speedup vs baseline: 2.5253x; 2.5253x over previous
//
#include <hip/hip_runtime.h>

typedef float f32x4 __attribute__((ext_vector_type(4)));
typedef short s16x8 __attribute__((ext_vector_type(8)));
typedef short s16x4 __attribute__((ext_vector_type(4)));
typedef unsigned short u16;

#define NB 8
#define NC 64
#define NN 4096
#define NK 8

__device__ __forceinline__ u16 f2bf_rne(float f) {
    unsigned u = __float_as_uint(f);
    u += 0x7FFFu + ((u >> 16) & 1u);
    return (u16)(u >> 16);
}
__device__ __forceinline__ u16 f2bf_trunc(float f) {
    return (u16)(__float_as_uint(f) >> 16);
}
__device__ __forceinline__ float bf2f(u16 v) {
    return __uint_as_float(((unsigned)v) << 16);
}

// ---------------------------------------------------------------------------
// Kernel 1: W' = [Wh(64); Wf(8); Wg(8)] (80x64) @ x[b] via MFMA.
// Weights staged to LDS coalesced; x loaded direct to B-frags.
// ---------------------------------------------------------------------------
__global__ __launch_bounds__(256, 4)
void precompute_qgh(const float* __restrict__ x,
                    const float* __restrict__ Wf,
                    const float* __restrict__ Wg,
                    const float* __restrict__ Wh,
                    u16* __restrict__ Qw, u16* __restrict__ Gw,
                    u16* __restrict__ Hw)
{
    const int b  = blockIdx.y;
    const int n0 = blockIdx.x * 64;
    const int t  = threadIdx.x;
    const int wave = t >> 6, lane = t & 63, col = lane & 15, quad = lane >> 4;
    const int n = n0 + wave * 16 + col;
    const float* xb = x + (size_t)b * NC * NN;

    __shared__ u16 Wl[80][72];

    float xv[16];
    #pragma unroll
    for (int s = 0; s < 2; s++)
        #pragma unroll
        for (int kk = 0; kk < 8; kk++)
            xv[s * 8 + kk] = xb[(size_t)(s * 32 + quad * 8 + kk) * NN + n];

    #pragma unroll
    for (int u = 0; u < 20; u++) {
        int v = t + u * 256, row = v >> 6, c = v & 63;
        float w = (row < 64) ? Wh[row * 64 + c]
                : (row < 72) ? Wf[(row - 64) * 64 + c]
                             : Wg[(row - 72) * 64 + c];
        Wl[row][c] = f2bf_rne(w);
    }
    __syncthreads();

    s16x8 bfrag[2];
    #pragma unroll
    for (int s = 0; s < 2; s++)
        #pragma unroll
        for (int kk = 0; kk < 8; kk++)
            ((u16*)&bfrag[s])[kk] = f2bf_rne(xv[s * 8 + kk]);

    f32x4 d[5];
    #pragma unroll
    for (int mt = 0; mt < 5; mt++) d[mt] = (f32x4){0.f, 0.f, 0.f, 0.f};
    #pragma unroll
    for (int s = 0; s < 2; s++) {
        #pragma unroll
        for (int mt = 0; mt < 5; mt++) {
            int row = (mt < 4) ? mt * 16 + col : 64 + col;
            s16x8 af = *(const s16x8*)(&Wl[row][s * 32 + quad * 8]);
            d[mt] = __builtin_amdgcn_mfma_f32_16x16x32_bf16(af, bfrag[s], d[mt], 0, 0, 0);
        }
    }

    u16* Hb = Hw + (size_t)b * NC * NN;
    #pragma unroll
    for (int mt = 0; mt < 4; mt++)
        #pragma unroll
        for (int r = 0; r < 4; r++)
            Hb[(size_t)(mt * 16 + quad * 4 + r) * NN + n] = f2bf_rne(d[mt][r]);
    #pragma unroll
    for (int r = 0; r < 4; r++) {
        int m = quad * 4 + r;
        u16 v = f2bf_rne(d[4][r]);
        if (m < 8) Qw[((size_t)b * NN + n) * NK + m]       = v;
        else       Gw[((size_t)b * NN + n) * NK + (m - 8)] = v;
    }
}

// ---------------------------------------------------------------------------
// Kernel 2 (v5): barrier-free flash attention via swapped PV operands.
//   O^T = V^T @ P^T : A-frag = H native [c][n] layout DIRECT from global,
//   D lands [c][i] (coalesced store, no transpose). Each wave owns 32 i-rows
//   (2 i-tiles) -> V-frag traffic amortized 2x. Only LDS: per-wave P buffer
//   (double-buffered) for the S->P^T layout transform. ZERO __syncthreads
//   in the main loop; waves fully independent.
// MFMA frags: A[m=lane&15][k=quad*8+..]; B[k=quad*8+..][n=lane&15];
//             D[row=quad*4+r][col=lane&15].
// ---------------------------------------------------------------------------
__global__ __launch_bounds__(256, 4)
void attention_fa(const u16* __restrict__ Qw, const u16* __restrict__ Gw,
                  const u16* __restrict__ Hw,
                  u16* __restrict__ Opart, float* __restrict__ Lpart,
                  int jspan)
{
    const int b    = blockIdx.y;
    const int i0   = blockIdx.x * 128;     // WG covers 128 i-rows (4 waves x 32)
    const int part = blockIdx.z;
    const int t    = threadIdx.x;
    const int wave = t >> 6, lane = t & 63, col = lane & 15, quad = lane >> 4;

    __shared__ u16 Pl[2][4][32][72];       // [buf][wave][i-row][j] = 36864 B

    const u16* Qb = Qw + (size_t)b * NN * NK;
    const u16* Gb = Gw + (size_t)b * NN * NK;
    const u16* Hb = Hw + (size_t)b * NC * NN;

    // Q A-frags for this wave's two 16-row i-tiles (quad!=0 zeroed: k-pad)
    s16x8 qfrag[2];
    #pragma unroll
    for (int it = 0; it < 2; it++) {
        qfrag[it] = *(const s16x8*)(Qb + (size_t)(i0 + wave * 32 + it * 16 + col) * NK);
        if (quad != 0) {
            #pragma unroll
            for (int i = 0; i < 8; i++) ((u16*)&qfrag[it])[i] = 0;
        }
    }
    s16x8 ones;
    #pragma unroll
    for (int i = 0; i < 8; i++) ((u16*)&ones)[i] = 0x3F80;   // bf16 1.0

    f32x4 oacc[4][2];      // [c-tile][i-tile]
    #pragma unroll
    for (int ct = 0; ct < 4; ct++)
        #pragma unroll
        for (int it = 0; it < 2; it++) oacc[ct][it] = (f32x4){0.f, 0.f, 0.f, 0.f};
    f32x4 lacc[2] = {(f32x4){0.f, 0.f, 0.f, 0.f}, (f32x4){0.f, 0.f, 0.f, 0.f}};

    const int jbase  = part * jspan;
    const int chunks = jspan / 64;

    for (int cc = 0; cc < chunks; cc++) {
        const int j0 = jbase + cc * 64;
        u16 (*Pw)[72] = Pl[cc & 1][wave];

        // G B-frags (k-junk in quads 1..3 nulled by zero-padded Q)
        s16x8 gf[4];
        #pragma unroll
        for (int jt = 0; jt < 4; jt++)
            gf[jt] = *(const s16x8*)(Gb + (size_t)(j0 + jt * 16 + col) * NK);

        // H A-frags for PV: native layout, 16B/lane, issued early to overlap
        s16x8 hf[2][4];
        #pragma unroll
        for (int s2 = 0; s2 < 2; s2++)
            #pragma unroll
            for (int ct = 0; ct < 4; ct++)
                hf[s2][ct] = *(const s16x8*)(Hb + (size_t)(ct * 16 + col) * NN
                                             + j0 + s2 * 32 + quad * 8);

        // S = QG^T -> exp -> P (per-wave LDS, row-major [i][j], pad 72)
        #pragma unroll
        for (int it = 0; it < 2; it++) {
            #pragma unroll
            for (int jt = 0; jt < 4; jt++) {
                f32x4 s = __builtin_amdgcn_mfma_f32_16x16x32_bf16(
                    qfrag[it], gf[jt], (f32x4){0.f, 0.f, 0.f, 0.f}, 0, 0, 0);
                #pragma unroll
                for (int r = 0; r < 4; r++)
                    Pw[it * 16 + quad * 4 + r][jt * 16 + col] = f2bf_trunc(__expf(s[r]));
            }
        }

        // P^T B-frags: lane(col,quad) reads P[row=it*16+col][s2*32+quad*8..]
        s16x8 pf[2][2];
        #pragma unroll
        for (int it = 0; it < 2; it++)
            #pragma unroll
            for (int s2 = 0; s2 < 2; s2++)
                pf[it][s2] = *(const s16x8*)(&Pw[it * 16 + col][s2 * 32 + quad * 8]);

        // row-sums: D[m][i] = sum_j P[i][j] (ones as A)
        #pragma unroll
        for (int it = 0; it < 2; it++)
            #pragma unroll
            for (int s2 = 0; s2 < 2; s2++)
                lacc[it] = __builtin_amdgcn_mfma_f32_16x16x32_bf16(
                    ones, pf[it][s2], lacc[it], 0, 0, 0);

        // O^T[c][i] += V^T[c][j] @ P^T[j][i]
        #pragma unroll
        for (int s2 = 0; s2 < 2; s2++)
            #pragma unroll
            for (int ct = 0; ct < 4; ct++)
                #pragma unroll
                for (int it = 0; it < 2; it++)
                    oacc[ct][it] = __builtin_amdgcn_mfma_f32_16x16x32_bf16(
                        hf[s2][ct], pf[it][s2], oacc[ct][it], 0, 0, 0);
    }

    // partial l: every m-row of lacc holds l_i; quad 0 lanes store 16 i's/it
    float* Lb = Lpart + ((size_t)part * NB + b) * NN + i0;
    if (quad == 0) {
        #pragma unroll
        for (int it = 0; it < 2; it++)
            Lb[wave * 32 + it * 16 + col] = lacc[it][0];
    }

    // partial O store: D[c][i] already coalesced over col=i (16 u16 = 32B runs)
    u16* Ob = Opart + ((size_t)part * NB + b) * NC * NN;
    #pragma unroll
    for (int ct = 0; ct < 4; ct++)
        #pragma unroll
        for (int it = 0; it < 2; it++)
            #pragma unroll
            for (int r = 0; r < 4; r++)
                Ob[(size_t)(ct * 16 + quad * 4 + r) * NN
                   + i0 + wave * 32 + it * 16 + col] = f2bf_rne(oacc[ct][it][r]);
}

// ---------------------------------------------------------------------------
// Kernel 3: out[b,c,i] = gamma * (sum_p O_p[b,c,i]) / (sum_p l_p[b,i]) + x
// ---------------------------------------------------------------------------
__global__ __launch_bounds__(256, 4)
void reduce_out(const u16* __restrict__ Opart, const float* __restrict__ Lpart,
                const float* __restrict__ x, const float* __restrict__ gamma,
                float* __restrict__ out, int parts)
{
    const int tid  = blockIdx.x * 256 + threadIdx.x;
    const int base = tid * 4;
    const int bc   = base >> 12;
    const int b    = bc >> 6;
    const int ii   = base & (NN - 1);

    float s[4] = {0.f, 0.f, 0.f, 0.f};
    float l[4] = {0.f, 0.f, 0.f, 0.f};
    for (int p = 0; p < parts; p++) {
        s16x4 ov = *(const s16x4*)(Opart + ((size_t)p * NB * NC + bc) * NN + ii);
        f32x4 lv = *(const f32x4*)(Lpart + ((size_t)p * NB + b) * NN + ii);
        #pragma unroll
        for (int e = 0; e < 4; e++) {
            s[e] += bf2f((u16)ov[e]);
            l[e] += lv[e];
        }
    }
    const float g = gamma[0];
    const f32x4 xv = *(const f32x4*)(x + base);
    f32x4 o;
    #pragma unroll
    for (int e = 0; e < 4; e++) o[e] = g * (s[e] / l[e]) + xv[e];
    *(f32x4*)(out + base) = o;
}

extern "C" void kernel_launch(void* const* d_in, const int* in_sizes, int n_in,
                              void* d_out, int out_size, void* d_ws, size_t ws_size,
                              hipStream_t stream) {
    const float* x     = (const float*)d_in[0];
    const float* Wf    = (const float*)d_in[1];
    const float* Wg    = (const float*)d_in[2];
    const float* Wh    = (const float*)d_in[3];
    const float* gamma = (const float*)d_in[4];
    float* out = (float*)d_out;

    u16* Qw = (u16*)d_ws;                       // [B][N][8]
    u16* Gw = Qw + (size_t)NB * NN * NK;        // [B][N][8]
    u16* Hw = Gw + (size_t)NB * NN * NK;        // [B][C][N]
    u16* Opart = Hw + (size_t)NB * NC * NN;     // [parts][B][C][N] bf16

    const size_t fixed = (size_t)(2 * NB * NN * NK + NB * NC * NN) * 2;
    int parts = 4;
    while (parts > 1) {
        size_t need = fixed + (size_t)parts * NB * NC * NN * 2
                            + (size_t)parts * NB * NN * 4 + 8192;
        if (need <= ws_size) break;
        parts >>= 1;
    }
    float* Lpart = (float*)(Opart + (size_t)parts * NB * NC * NN);
    const int jspan = NN / parts;

    precompute_qgh<<<dim3(64, NB), 256, 0, stream>>>(x, Wf, Wg, Wh, Qw, Gw, Hw);
    attention_fa<<<dim3(NN / 128, NB, parts), 256, 0, stream>>>(
        Qw, Gw, Hw, Opart, Lpart, jspan);
    reduce_out<<<dim3((NB * NC * NN) / 1024), 256, 0, stream>>>(
        Opart, Lpart, x, gamma, out, parts);
}

// Round 6
// 142.084 us; speedup vs baseline: 2.6069x; 1.0323x over previous
//
#include <hip/hip_runtime.h>

typedef float f32x4 __attribute__((ext_vector_type(4)));
typedef short s16x8 __attribute__((ext_vector_type(8)));
typedef short s16x4 __attribute__((ext_vector_type(4)));
typedef unsigned short u16;

#define NB 8
#define NC 64
#define NN 4096
#define NK 8

__device__ __forceinline__ u16 f2bf_rne(float f) {
    unsigned u = __float_as_uint(f);
    u += 0x7FFFu + ((u >> 16) & 1u);
    return (u16)(u >> 16);
}
__device__ __forceinline__ u16 f2bf_trunc(float f) {
    return (u16)(__float_as_uint(f) >> 16);
}
__device__ __forceinline__ float bf2f(u16 v) {
    return __uint_as_float(((unsigned)v) << 16);
}

// ---------------------------------------------------------------------------
// Kernel 0: one-time weight prep. W' = [Wh(64); Wf|Wg(16)] (80x64) packed as
// MFMA A-frags: Wfrag[(mt*2+s)*64 + lane] = 8 bf16 (16B). mt 0..4, s = k-half.
// A[m=col][k=s*32+quad*8+kk]. One WG; scattered reads happen ONCE here.
// ---------------------------------------------------------------------------
__global__ void prep_weights(const float* __restrict__ Wf,
                             const float* __restrict__ Wg,
                             const float* __restrict__ Wh,
                             u16* __restrict__ Wfrag)
{
    const int t = threadIdx.x;
    #pragma unroll
    for (int u = 0; u < 3; u++) {
        int e = t + u * 256;
        if (e >= 640) break;
        int mt = e >> 7, s = (e >> 6) & 1, lane = e & 63;
        int col = lane & 15, quad = lane >> 4;
        s16x8 v;
        #pragma unroll
        for (int kk = 0; kk < 8; kk++) {
            int c = s * 32 + quad * 8 + kk;
            float w = (mt < 4) ? Wh[(mt * 16 + col) * 64 + c]
                    : (col < 8 ? Wf[col * 64 + c] : Wg[(col - 8) * 64 + c]);
            ((u16*)&v)[kk] = f2bf_rne(w);
        }
        *(s16x8*)(Wfrag + e * 8) = v;
    }
}

// ---------------------------------------------------------------------------
// Kernel 1: projections via MFMA, barrier-free & LDS-free. Each wave owns 16
// positions; A-frags read coalesced (b128) from Wfrag; x gathered to B-frags.
// Outputs bf16: Hw [B][C][N]; Qw/Gw [B][N][8].
// ---------------------------------------------------------------------------
__global__ __launch_bounds__(256, 4)
void precompute_qgh(const float* __restrict__ x,
                    const u16* __restrict__ Wfrag,
                    u16* __restrict__ Qw, u16* __restrict__ Gw,
                    u16* __restrict__ Hw)
{
    const int b  = blockIdx.y;
    const int n0 = blockIdx.x * 64;
    const int t  = threadIdx.x;
    const int wave = t >> 6, lane = t & 63, col = lane & 15, quad = lane >> 4;
    const int n = n0 + wave * 16 + col;
    const float* xb = x + (size_t)b * NC * NN;

    float xv[16];
    #pragma unroll
    for (int s = 0; s < 2; s++)
        #pragma unroll
        for (int kk = 0; kk < 8; kk++)
            xv[s * 8 + kk] = xb[(size_t)(s * 32 + quad * 8 + kk) * NN + n];

    s16x8 bfrag[2];
    #pragma unroll
    for (int s = 0; s < 2; s++)
        #pragma unroll
        for (int kk = 0; kk < 8; kk++)
            ((u16*)&bfrag[s])[kk] = f2bf_rne(xv[s * 8 + kk]);

    f32x4 d[5];
    #pragma unroll
    for (int mt = 0; mt < 5; mt++) d[mt] = (f32x4){0.f, 0.f, 0.f, 0.f};
    #pragma unroll
    for (int s = 0; s < 2; s++) {
        #pragma unroll
        for (int mt = 0; mt < 5; mt++) {
            s16x8 af = *(const s16x8*)(Wfrag + ((mt * 2 + s) * 64 + lane) * 8);
            d[mt] = __builtin_amdgcn_mfma_f32_16x16x32_bf16(af, bfrag[s], d[mt], 0, 0, 0);
        }
    }

    u16* Hb = Hw + (size_t)b * NC * NN;
    #pragma unroll
    for (int mt = 0; mt < 4; mt++)
        #pragma unroll
        for (int r = 0; r < 4; r++)
            Hb[(size_t)(mt * 16 + quad * 4 + r) * NN + n] = f2bf_rne(d[mt][r]);
    #pragma unroll
    for (int r = 0; r < 4; r++) {
        int m = quad * 4 + r;
        u16 v = f2bf_rne(d[4][r]);
        if (m < 8) Qw[((size_t)b * NN + n) * NK + m]       = v;
        else       Gw[((size_t)b * NN + n) * NK + (m - 8)] = v;
    }
}

// ---------------------------------------------------------------------------
// Kernel 2: flash attention over a j-partition (r2 structure — best measured).
// WG = 64 i-rows (4 waves x 16), j-chunks of 64. V register-prefetched one
// chunk ahead; G at loop top. Row sums via ones-B-frag MFMA. Writes
// unnormalized partial O (bf16 [part][b][c][i] via LDS transpose), partial l.
// MFMA frags: A[m=lane&15][k=quad*8+jj]; B[k=quad*8+jj][n=lane&15];
//             D[row=quad*4+r][col=lane&15].
// ---------------------------------------------------------------------------
__global__ __launch_bounds__(256, 8)
void attention_fa(const u16* __restrict__ Qw, const u16* __restrict__ Gw,
                  const u16* __restrict__ Hw,
                  u16* __restrict__ Opart, float* __restrict__ Lpart,
                  int jspan)
{
    const int b    = blockIdx.y;
    const int i0   = blockIdx.x * 64;
    const int part = blockIdx.z;
    const int t    = threadIdx.x;
    const int wave = t >> 6, lane = t & 63, col = lane & 15, quad = lane >> 4;

    __shared__ u16 Vlds[64][72];
    __shared__ u16 Plds[4][16][72];

    const u16* Qb = Qw + (size_t)b * NN * NK;
    const u16* Gb = Gw + (size_t)b * NN * NK;
    const u16* Hb = Hw + (size_t)b * NC * NN;

    s16x8 qfrag = *(const s16x8*)(Qb + (size_t)(i0 + wave * 16 + col) * NK);
    if (quad != 0) {
        #pragma unroll
        for (int i = 0; i < 8; i++) ((u16*)&qfrag)[i] = 0;
    }
    s16x8 ones;
    #pragma unroll
    for (int i = 0; i < 8; i++) ((u16*)&ones)[i] = 0x3F80;

    f32x4 oacc[4];
    #pragma unroll
    for (int ct = 0; ct < 4; ct++) oacc[ct] = (f32x4){0.f, 0.f, 0.f, 0.f};
    f32x4 lacc = (f32x4){0.f, 0.f, 0.f, 0.f};

    const int jbase  = part * jspan;
    const int chunks = jspan / 64;
    const int vc = t >> 3, vseg = t & 7;

    s16x8 vreg[2];
    #pragma unroll
    for (int u = 0; u < 2; u++)
        vreg[u] = *(const s16x8*)(Hb + (size_t)(u * 32 + vc) * NN + jbase + vseg * 8);

    for (int cc = 0; cc < chunks; cc++) {
        const int j0 = jbase + cc * 64;

        // G fragments for this chunk
        s16x8 gf[4];
        #pragma unroll
        for (int jt = 0; jt < 4; jt++)
            gf[jt] = *(const s16x8*)(Gb + (size_t)(j0 + jt * 16 + col) * NK);

        // V prefetch for next chunk (last-iter overread lands in Opart — benign)
        s16x8 vnext[2];
        #pragma unroll
        for (int u = 0; u < 2; u++)
            vnext[u] = *(const s16x8*)(Hb + (size_t)(u * 32 + vc) * NN + j0 + 64 + vseg * 8);

        __syncthreads();               // prev PV reads of Vlds complete
        #pragma unroll
        for (int u = 0; u < 2; u++)
            *(s16x8*)(&Vlds[u * 32 + vc][vseg * 8]) = vreg[u];

        // QK^T -> exp -> P (trunc: bias cancels, l uses same bf16 P)
        #pragma unroll
        for (int jt = 0; jt < 4; jt++) {
            f32x4 s = __builtin_amdgcn_mfma_f32_16x16x32_bf16(
                qfrag, gf[jt], (f32x4){0.f, 0.f, 0.f, 0.f}, 0, 0, 0);
            #pragma unroll
            for (int r = 0; r < 4; r++)
                Plds[wave][quad * 4 + r][jt * 16 + col] = f2bf_trunc(__expf(s[r]));
        }

        __syncthreads();               // V writes visible

        // PV + row-sum MFMAs
        #pragma unroll
        for (int s2 = 0; s2 < 2; s2++) {
            s16x8 af = *(const s16x8*)(&Plds[wave][col][s2 * 32 + quad * 8]);
            lacc = __builtin_amdgcn_mfma_f32_16x16x32_bf16(af, ones, lacc, 0, 0, 0);
            #pragma unroll
            for (int ct = 0; ct < 4; ct++) {
                s16x8 bf = *(const s16x8*)(&Vlds[ct * 16 + col][s2 * 32 + quad * 8]);
                oacc[ct] = __builtin_amdgcn_mfma_f32_16x16x32_bf16(af, bf, oacc[ct], 0, 0, 0);
            }
        }
        vreg[0] = vnext[0]; vreg[1] = vnext[1];
    }

    float* Lb = Lpart + ((size_t)part * NB + b) * NN + i0;
    if (col == 0) {
        #pragma unroll
        for (int r = 0; r < 4; r++) Lb[wave * 16 + quad * 4 + r] = lacc[r];
    }

    // transpose O to [c][i] through LDS (reuse Plds), coalesced store
    __syncthreads();
    u16 (*OT)[72] = (u16(*)[72])Plds;
    #pragma unroll
    for (int ct = 0; ct < 4; ct++)
        #pragma unroll
        for (int r = 0; r < 4; r++)
            OT[ct * 16 + col][wave * 16 + quad * 4 + r] = f2bf_rne(oacc[ct][r]);
    __syncthreads();

    u16* Ob = Opart + ((size_t)part * NB + b) * NC * NN;
    #pragma unroll
    for (int u = 0; u < 2; u++) {
        int c = u * 32 + vc;
        *(s16x8*)(Ob + (size_t)c * NN + i0 + vseg * 8) = *(const s16x8*)(&OT[c][vseg * 8]);
    }
}

// ---------------------------------------------------------------------------
// Kernel 3: out[b,c,i] = gamma * (sum_p O_p[b,c,i]) / (sum_p l_p[b,i]) + x
// ---------------------------------------------------------------------------
__global__ __launch_bounds__(256, 4)
void reduce_out(const u16* __restrict__ Opart, const float* __restrict__ Lpart,
                const float* __restrict__ x, const float* __restrict__ gamma,
                float* __restrict__ out, int parts)
{
    const int tid  = blockIdx.x * 256 + threadIdx.x;
    const int base = tid * 4;
    const int bc   = base >> 12;
    const int b    = bc >> 6;
    const int ii   = base & (NN - 1);

    float s[4] = {0.f, 0.f, 0.f, 0.f};
    float l[4] = {0.f, 0.f, 0.f, 0.f};
    for (int p = 0; p < parts; p++) {
        s16x4 ov = *(const s16x4*)(Opart + ((size_t)p * NB * NC + bc) * NN + ii);
        f32x4 lv = *(const f32x4*)(Lpart + ((size_t)p * NB + b) * NN + ii);
        #pragma unroll
        for (int e = 0; e < 4; e++) {
            s[e] += bf2f((u16)ov[e]);
            l[e] += lv[e];
        }
    }
    const float g = gamma[0];
    const f32x4 xv = *(const f32x4*)(x + base);
    f32x4 o;
    #pragma unroll
    for (int e = 0; e < 4; e++) o[e] = g * (s[e] / l[e]) + xv[e];
    *(f32x4*)(out + base) = o;
}

extern "C" void kernel_launch(void* const* d_in, const int* in_sizes, int n_in,
                              void* d_out, int out_size, void* d_ws, size_t ws_size,
                              hipStream_t stream) {
    const float* x     = (const float*)d_in[0];
    const float* Wf    = (const float*)d_in[1];
    const float* Wg    = (const float*)d_in[2];
    const float* Wh    = (const float*)d_in[3];
    const float* gamma = (const float*)d_in[4];
    float* out = (float*)d_out;

    u16* Qw = (u16*)d_ws;                       // [B][N][8]
    u16* Gw = Qw + (size_t)NB * NN * NK;        // [B][N][8]
    u16* Hw = Gw + (size_t)NB * NN * NK;        // [B][C][N]
    u16* Opart = Hw + (size_t)NB * NC * NN;     // [parts][B][C][N] bf16

    const size_t fixed = (size_t)(2 * NB * NN * NK + NB * NC * NN) * 2;
    int parts = 8;
    while (parts > 1) {
        size_t need = fixed + (size_t)parts * NB * NC * NN * 2
                            + (size_t)parts * NB * NN * 4
                            + 640 * 16 + 8192;
        if (need <= ws_size) break;
        parts >>= 1;
    }
    float* Lpart = (float*)(Opart + (size_t)parts * NB * NC * NN);
    u16* Wfrag = (u16*)(Lpart + (size_t)parts * NB * NN);
    const int jspan = NN / parts;

    prep_weights<<<1, 256, 0, stream>>>(Wf, Wg, Wh, Wfrag);
    precompute_qgh<<<dim3(64, NB), 256, 0, stream>>>(x, Wfrag, Qw, Gw, Hw);
    attention_fa<<<dim3(64, NB, parts), 256, 0, stream>>>(
        Qw, Gw, Hw, Opart, Lpart, jspan);
    reduce_out<<<dim3((NB * NC * NN) / 1024), 256, 0, stream>>>(
        Opart, Lpart, x, gamma, out, parts);
}